// Round 8
// baseline (234.877 us; speedup 1.0000x reference)
//
#include <hip/hip_runtime.h>
#include <hip/hip_bf16.h>

// 2-layer GCN encoder: (GCNConv -> BatchNorm1d(train) -> PReLU) x 2
// N=50000, E=800000, D=128. Inputs f32 (probed), edge_index int64 (probed),
// output f32. Internal: GEMM/agg buffers bf16, math f32.
//
// R21: k_agg uint2 gather -- 2 edges per wave instruction. Degree ~
// Poisson(16); R19's 16-edge batch gave deg-17..31 nodes (43%) two serial
// LLC round-trips. Now: 32 lanes per edge at 8B/lane (uint2), lanes 0-31 =
// edge 2g / lanes 32-63 = edge 2g+1, both indices scalar-pipe. Predicated
// batch covers 32 edges -> ceil(deg/32) = 1 round-trip for 99.97% of nodes;
// gather instruction count halves; 32 edges in flight per wave. Fold =
// shfl_xor(32). Stats via [4][128] LDS, same statsp semantics; aggbuf stays
// row-major (gemm/bn readers untouched). bin/degfill (R20), gemm (R18), bn
// unchanged.
//
// ws layout (bytes):
//   [0       .. +200000)   dinv f32[NN]
//   [200704  .. +8)        flags: [0]=int64?, [1]=bf16-floats?
//   [201728  .. +784)      tailc int[196] (zeroed by memset; bucket fills)
//   [404800  .. +200000)   rowptr int[NN] (row starts, gapped CSR)
//   [604816  .. +200000)   rowend int[NN]
//   [806400  .. +65536)    stats1p f32[64][256]
//   [871936  .. +65536)    stats2p f32[64][256]
//   [1048576 .. +3.6MB)    csr_src int[196*4608]
//   [4718592 .. +12.8MB)   hbuf  bf16[NN*DD] packed-slot layout (dinv-scaled)
//   [17518592.. +32768)    wp1 bf16[128*128] swizzled
//   [17551360.. +32768)    wp2 bf16[128*128] swizzled
//   [30056448.. +12.8MB)   aggbuf bf16[NN*DD] row-major
//   [42856448.. +3.6MB)    binned uint[196*4608] packed (src<<16)|dst

typedef __hip_bfloat16 bf16;
typedef __attribute__((ext_vector_type(8))) short short8;   // 8 bf16 = 4 VGPR
typedef __attribute__((ext_vector_type(4))) float f32x4;    // MFMA accumulator

#define NN 50000
#define NE 800000
#define DD 128
#define BN_EPS 1e-5f
#define NBIN 800         // k_bin blocks
#define BIN_CHUNK 1000   // NE / NBIN exactly
#define CAP 4608         // per-bucket capacity (mean 4096 + 8 sigma)
#define NBKT 196         // ceil(50000 / 256)

__device__ __forceinline__ float b2f(bf16 v) { return __bfloat162float(v); }
__device__ __forceinline__ float ldf(const void* p, size_t idx, int isbf) {
  return isbf ? b2f(((const bf16*)p)[idx]) : ((const float*)p)[idx];
}
__device__ __forceinline__ int lde(const void* ei, size_t idx, int is64) {
  return is64 ? (int)((const long long*)ei)[idx] : ((const int*)ei)[idx];
}
__device__ __forceinline__ unsigned int f2bs(float v) {
  bf16 b = __float2bfloat16(v);
  return (unsigned int)*reinterpret_cast<unsigned short*>(&b);
}
__device__ __forceinline__ float bslo(unsigned int u) { return __uint_as_float(u << 16); }
__device__ __forceinline__ float bshi(unsigned int u) { return __uint_as_float(u & 0xFFFF0000u); }
__device__ __forceinline__ float s2f(short v) {
  return __uint_as_float(((unsigned int)(unsigned short)v) << 16);
}

// 800 blocks x 256. Per-block dtype self-probe; block 0 publishes flags;
// blocks 0..63 swizzle W1, 64..127 swizzle W2; all bin their 1000-edge chunk
// into packed binned[] at zero-based bucket counters (tailc pre-zeroed).
// Packed word u = (src<<16) | dst; bucket = (u>>8)&0xFF, local = u&0xFF.
__global__ __launch_bounds__(256) void k_bin(const int* ei_i, const unsigned short* x16,
                                             const void* W1, const void* W2,
                                             unsigned short* wp1, unsigned short* wp2,
                                             int* flags, int* tailc, unsigned int* binned) {
  __shared__ int cnt[NBKT], cur[NBKT], gb[NBKT], sflags[2];
  __shared__ unsigned int ebuf[BIN_CHUNK];  // 4 KB
  const int tid = threadIdx.x;
  const int bid = blockIdx.x;
  if (tid < 64) {
    unsigned long long m1 = __ballot(ei_i[2 * tid + 1] != 0);
    int ex = (x16[2 * tid] >> 7) & 0xFF;
    unsigned long long m2 = __ballot(ex >= 90 && ex <= 140);
    if (tid == 0) {
      sflags[0] = (m1 == 0ull) ? 1 : 0;
      sflags[1] = (__popcll(m2) >= 48) ? 1 : 0;
    }
  }
  if (tid < NBKT) { cnt[tid] = 0; cur[tid] = 0; }
  __syncthreads();
  const int is64 = sflags[0], isbf = sflags[1];
  if (bid == 0 && tid == 0) { flags[0] = is64; flags[1] = isbf; }
  if (bid < 128) {  // W swizzle side-job
    const void* W = bid < 64 ? W1 : W2;
    unsigned short* wp = bid < 64 ? wp1 : wp2;
    int idx = (bid & 63) * 256 + tid;
    int k = idx >> 7, n = idx & 127;
    wp[(k >> 3) * 1024 + n * 8 + (k & 7)] = (unsigned short)f2bs(ldf(W, idx, isbf));
  }
  const void* ei = (const void*)ei_i;
  const int e0 = bid * BIN_CHUNK;
  for (int t = tid; t < BIN_CHUNK; t += 256) {
    int s = lde(ei, (size_t)(e0 + t), is64);
    int d = lde(ei, (size_t)NE + e0 + t, is64);
    ebuf[t] = ((unsigned)s << 16) | (unsigned)d;
    atomicAdd(&cnt[d >> 8], 1);
  }
  __syncthreads();
  if (tid < NBKT && cnt[tid] > 0) gb[tid] = tid * CAP + atomicAdd(&tailc[tid], cnt[tid]);
  __syncthreads();
  for (int t = tid; t < BIN_CHUNK; t += 256) {
    unsigned int u = ebuf[t];
    int b = (int)((u >> 8) & 0xFF);
    int r = atomicAdd(&cur[b], 1);
    binned[gb[b] + r] = u;
  }
}

// Per-bucket (256 nodes): degree hist (LDS) -> dinv/rowptr/rowend, then exact
// CSR fill with LDS cursors. 196 blocks x 512 (edge passes use all 512, scan
// uses 256). Packed u: src=u>>16, local=u&0xFF.
__global__ __launch_bounds__(512) void k_degfill(const unsigned int* binned, const int* tailc,
                                                 float* dinv, int* rowptr, int* rowend,
                                                 int* csr_src) {
  __shared__ int hist[256];
  const int b = blockIdx.x;
  const int t = threadIdx.x;
  if (t < 256) hist[t] = 0;
  __syncthreads();
  const int eb = b * CAP, ee = eb + tailc[b];
  for (int e = eb + t; e < ee; e += 512) atomicAdd(&hist[binned[e] & 0xFF], 1);
  __syncthreads();
  int h = 0;
  if (t < 256) h = hist[t];
  __syncthreads();
  for (int off = 1; off < 256; off <<= 1) {  // inclusive scan over 256
    int u = 0;
    if (t < 256 && t >= off) u = hist[t - off];
    __syncthreads();
    if (t < 256) hist[t] += u;
    __syncthreads();
  }
  if (t < 256) {
    int start = eb + hist[t] - h;  // exclusive prefix, global position
    int node = b * 256 + t;
    if (node < NN) {
      rowptr[node] = start;
      rowend[node] = start + h;
      dinv[node] = rsqrtf((float)(h + 1));  // +1 self-loop
    }
    hist[t] = start;  // repurpose as fill cursor
  }
  __syncthreads();
  for (int e = eb + t; e < ee; e += 512) {
    unsigned int u = binned[e];
    int pos = atomicAdd(&hist[u & 0xFF], 1);
    csr_src[pos] = (int)(u >> 16);
  }
}

// MFMA GEMM, 64 rows/block (782 blocks). out = dinv-prescaled bf16 in
// packed-slot layout: row r, u32 slot s holds bf16 pair (col s, col s+64).
// W pre-swizzled (wp), raw LDS copy. XMODE 0: layer-1 input (probe f32/bf16).
// XMODE 2: aggbuf bf16 + fused BN1 (stats from 64-copy partials statsp).
// Blocks 0..63 zero zstats (consumed by the NEXT kernel's atomics --
// stream-ordered, safe).
template <int XMODE>
__global__ __launch_bounds__(256) void k_gemm(const void* in_, const unsigned short* wp,
                                              const int* flags, const float* dinv,
                                              const float* statsp, const void* g,
                                              const void* be, const void* al,
                                              float* zstats, unsigned int* out) {
  __shared__ alignas(16) short sW[16 * 128 * 8];  // 32 KB
  __shared__ float sSc[DD], sSh[DD], sAl;
  const int isbf = flags[1];
  const int tid = threadIdx.x;

  if (blockIdx.x < 64) zstats[blockIdx.x * 256 + tid] = 0.f;
  {
    const short8* src = (const short8*)wp;
    short8* dst = (short8*)sW;
#pragma unroll
    for (int i = 0; i < 8; i++) dst[tid + i * 256] = src[tid + i * 256];
  }
  if (XMODE == 2) {
    if (tid < DD) {
      float s = 0.f, q = 0.f;
#pragma unroll 8
      for (int k = 0; k < 64; k++) {
        s += statsp[k * 256 + tid];
        q += statsp[k * 256 + 128 + tid];
      }
      const float inv_n = 1.0f / NN;
      float mu = s * inv_n;
      float var = q * inv_n - mu * mu;
      float sc = rsqrtf(var + BN_EPS) * ldf(g, tid, isbf);
      sSc[tid] = sc;
      sSh[tid] = ldf(be, tid, isbf) - mu * sc;
    }
    if (tid == 0) sAl = ldf(al, 0, isbf);
  }
  __syncthreads();

  const int wave = tid >> 6;
  const int lane = tid & 63;
  const int quad = lane >> 4;
  const int m16 = lane & 15;
  const int r0 = blockIdx.x * 64 + wave * 16;

  f32x4 acc[8];
#pragma unroll
  for (int n = 0; n < 8; n++) acc[n] = (f32x4){0.f, 0.f, 0.f, 0.f};

#pragma unroll
  for (int q = 0; q < 4; q++) {
    const int kq = q * 32 + quad * 8;
    short8 af;
    {
      int row = r0 + m16;
      row = row < NN ? row : NN - 1;  // clamp; garbage rows never stored
      if (XMODE == 2) {
        short8 raw = *(const short8*)((const short*)in_ + (size_t)row * DD + kq);
        short8 f;
#pragma unroll
        for (int jj = 0; jj < 8; jj++) {
          float y = s2f(raw[jj]);
          y = y * sSc[kq + jj] + sSh[kq + jj];
          y = y > 0.f ? y : sAl * y;
          f[jj] = (short)f2bs(y);
        }
        af = f;
      } else if (isbf) {
        af = *(const short8*)((const short*)in_ + (size_t)row * DD + kq);
      } else {
        const float* ap = (const float*)in_ + (size_t)row * DD + kq;
        const float4 u0 = *(const float4*)ap;
        const float4 u1 = *(const float4*)(ap + 4);
        float v[8] = {u0.x, u0.y, u0.z, u0.w, u1.x, u1.y, u1.z, u1.w};
        short8 f;
#pragma unroll
        for (int jj = 0; jj < 8; jj++) f[jj] = (short)f2bs(v[jj]);
        af = f;
      }
    }
    const int c = q * 4 + quad;
    const short* bp = sW + c * 1024 + m16 * 8;
#pragma unroll
    for (int n = 0; n < 8; n++) {
      const short8 bfrag = *(const short8*)(bp + n * 128);
      acc[n] = __builtin_amdgcn_mfma_f32_16x16x32_bf16(af, bfrag, acc[n], 0, 0, 0);
    }
  }

#pragma unroll
  for (int r = 0; r < 4; r++) {
    int row = r0 + quad * 4 + r;
    if (row < NN) {
      float di = dinv[row];
      unsigned int* orow = out + (size_t)row * 64;
#pragma unroll
      for (int n = 0; n < 4; n++) {
        unsigned int p = (f2bs(di * acc[n + 4][r]) << 16) | f2bs(di * acc[n][r]);
        orow[n * 16 + m16] = p;
      }
    }
  }
}

// One wave per node (12500 blocks = 50000 waves). uint2 gather: 32 lanes per
// edge at 8B/lane; lanes 0-31 take edge 2g, lanes 32-63 edge 2g+1 (both
// indices scalar-pipe via readfirstlane'd e). One batch = 16 gathers = 32
// edges in flight = 1 LLC round-trip for 99.97% of nodes. Remainder uses the
// R19 clamp+mask trick per half. Fold halves with shfl_xor(32).
// Lane j<32 owns u32 slots {2j, 2j+1} = cols {2j, 2j+1} (lo) / {2j+64,
// 2j+65} (hi). aggbuf stays row-major bf16[128].
__global__ __launch_bounds__(256) void k_agg(const unsigned int* hs, const float* dinv,
                                             const int* rowptr, const int* rowend,
                                             const int* csr_src, const void* bias,
                                             const int* flags, unsigned short* out,
                                             float* statsp) {
  const int tid = threadIdx.x;
  const int wv = tid >> 6;
  const int w = (blockIdx.x * 256 + tid) >> 6;   // never >= NN (12500*4 == NN)
  const int lane = tid & 63;
  const int j = lane & 31;
  const bool hiHalf = lane >= 32;
  const uint2* hs2 = (const uint2*)hs;           // row = 32 uint2
  const float dd_ = dinv[w];

  float ax0, ay0, ax1, ay1;
  {
    const uint2 own = hs2[(size_t)w * 32 + j];
    if (!hiHalf) {  // self-loop counted once
      ax0 = bslo(own.x); ay0 = bshi(own.x);
      ax1 = bslo(own.y); ay1 = bshi(own.y);
    } else {
      ax0 = 0.f; ay0 = 0.f; ax1 = 0.f; ay1 = 0.f;
    }
  }
  int e = __builtin_amdgcn_readfirstlane(rowptr[w]);
  const int e1 = __builtin_amdgcn_readfirstlane(rowend[w]);

  for (; e + 32 <= e1; e += 32) {
    int sA[16], sB[16];
#pragma unroll
    for (int g = 0; g < 16; g++) {
      sA[g] = csr_src[e + 2 * g];
      sB[g] = csr_src[e + 2 * g + 1];
    }
    uint2 v[16];
#pragma unroll
    for (int g = 0; g < 16; g++) {
      const int s = hiHalf ? sB[g] : sA[g];
      v[g] = hs2[(size_t)s * 32 + j];
    }
#pragma unroll
    for (int g = 0; g < 16; g++) {
      ax0 += bslo(v[g].x); ay0 += bshi(v[g].x);
      ax1 += bslo(v[g].y); ay1 += bshi(v[g].y);
    }
  }
  const int r = e1 - e;  // 0..31, wave-uniform
  if (r > 0) {
    int sA[16], sB[16];
#pragma unroll
    for (int g = 0; g < 16; g++) {
      sA[g] = csr_src[e + (2 * g < r ? 2 * g : 0)];
      sB[g] = csr_src[e + (2 * g + 1 < r ? 2 * g + 1 : 0)];
    }
    uint2 v[16];
#pragma unroll
    for (int g = 0; g < 16; g++) {
      const int s = hiHalf ? sB[g] : sA[g];
      v[g] = hs2[(size_t)s * 32 + j];
    }
#pragma unroll
    for (int g = 0; g < 16; g++) {
      const int kk = hiHalf ? (2 * g + 1) : (2 * g);
      const float m = (kk < r) ? 1.f : 0.f;
      ax0 += m * bslo(v[g].x); ay0 += m * bshi(v[g].x);
      ax1 += m * bslo(v[g].y); ay1 += m * bshi(v[g].y);
    }
  }

  // fold edge-halves: lanes l and l+32 hold the two partial streams
  ax0 += __shfl_xor(ax0, 32); ay0 += __shfl_xor(ay0, 32);
  ax1 += __shfl_xor(ax1, 32); ay1 += __shfl_xor(ay1, 32);

  __shared__ float ssum[4][128], ssq[4][128];  // 4 KB
  const int isbf = flags[1];
  if (!hiHalf) {
    const int c0 = 2 * j;
    const float oA0 = dd_ * ax0 + ldf(bias, c0, isbf);        // col 2j
    const float oA1 = dd_ * ax1 + ldf(bias, c0 + 1, isbf);    // col 2j+1
    const float oB0 = dd_ * ay0 + ldf(bias, c0 + 64, isbf);   // col 2j+64
    const float oB1 = dd_ * ay1 + ldf(bias, c0 + 65, isbf);   // col 2j+65
    unsigned int* orow32 = (unsigned int*)(out + (size_t)w * DD);
    orow32[j] = (f2bs(oA1) << 16) | f2bs(oA0);
    orow32[32 + j] = (f2bs(oB1) << 16) | f2bs(oB0);
    ssum[wv][c0] = oA0;      ssq[wv][c0] = oA0 * oA0;
    ssum[wv][c0 + 1] = oA1;  ssq[wv][c0 + 1] = oA1 * oA1;
    ssum[wv][c0 + 64] = oB0; ssq[wv][c0 + 64] = oB0 * oB0;
    ssum[wv][c0 + 65] = oB1; ssq[wv][c0 + 65] = oB1 * oB1;
  }
  __syncthreads();
  if (tid < 128) {
    const float s = ssum[0][tid] + ssum[1][tid] + ssum[2][tid] + ssum[3][tid];
    const float q = ssq[0][tid] + ssq[1][tid] + ssq[2][tid] + ssq[3][tid];
    float* p = statsp + (blockIdx.x & 63) * 256;
    atomicAdd(&p[tid], s);
    atomicAdd(&p[128 + tid], q);
  }
}

// Final BN+PReLU: 1024 grid-stride blocks. Prologue sums the 64 stat copies
// into LDS sc/sh (one rsqrt per column per block, not per element).
__global__ __launch_bounds__(256) void k_bn_apply(const unsigned int* x32, const float* statsp,
                                                  const void* g, const void* be, const void* al,
                                                  const int* flags, void* out) {
  __shared__ float sSc[DD], sSh[DD], sAl;
  const int tid = threadIdx.x;
  const int isbf = flags[1];
  if (tid < DD) {
    float s = 0.f, q = 0.f;
#pragma unroll 8
    for (int k = 0; k < 64; k++) {
      s += statsp[k * 256 + tid];
      q += statsp[k * 256 + 128 + tid];
    }
    const float inv_n = 1.0f / NN;
    float mu = s * inv_n;
    float var = q * inv_n - mu * mu;
    float sc = rsqrtf(var + BN_EPS) * ldf(g, tid, isbf);
    sSc[tid] = sc;
    sSh[tid] = ldf(be, tid, isbf) - mu * sc;
  }
  if (tid == 0) sAl = ldf(al, 0, isbf);
  __syncthreads();
  const float alpha = sAl;
  for (int i4 = blockIdx.x * 256 + tid; i4 < NN * 32; i4 += gridDim.x * 256) {
    int jq = (i4 & 31) * 4;
    const uint2 xv = ((const uint2*)x32)[i4];
    float xa[4] = {bslo(xv.x), bshi(xv.x), bslo(xv.y), bshi(xv.y)};
    float y[4];
#pragma unroll
    for (int u = 0; u < 4; u++) {
      int j = jq + u;
      float v = xa[u] * sSc[j] + sSh[j];
      y[u] = v > 0.f ? v : alpha * v;
    }
    if (isbf) {
      uint2 o;
      o.x = (f2bs(y[1]) << 16) | f2bs(y[0]);
      o.y = (f2bs(y[3]) << 16) | f2bs(y[2]);
      ((uint2*)out)[i4] = o;
    } else {
      float4 o = {y[0], y[1], y[2], y[3]};
      ((float4*)out)[i4] = o;
    }
  }
}

extern "C" void kernel_launch(void* const* d_in, const int* in_sizes, int n_in,
                              void* d_out, int out_size, void* d_ws, size_t ws_size,
                              hipStream_t stream) {
  const void* x = d_in[0];
  const int* ei = (const int*)d_in[1];
  const void* W1 = d_in[2];
  const void* b1 = d_in[3];
  const void* g1 = d_in[4];
  const void* be1 = d_in[5];
  const void* a1 = d_in[6];
  const void* W2 = d_in[7];
  const void* b2 = d_in[8];
  const void* g2 = d_in[9];
  const void* be2 = d_in[10];
  const void* a2 = d_in[11];

  char* w = (char*)d_ws;
  float* dinv = (float*)w;                              // 200000
  int* flags = (int*)(w + 200704);                      // 8
  int* tailc = (int*)(w + 201728);                      // 784 (196 int)
  int* rowptr = (int*)(w + 404800);                     // 200000
  int* rowend = (int*)(w + 604816);                     // 200000
  float* stats1p = (float*)(w + 806400);                // 65536
  float* stats2p = (float*)(w + 871936);                // 65536
  int* csr_src = (int*)(w + 1048576);                   // 3612672
  unsigned int* hbuf = (unsigned int*)(w + 4718592);    // 12800000
  unsigned short* wp1 = (unsigned short*)(w + 17518592);   // 32768
  unsigned short* wp2 = (unsigned short*)(w + 17551360);   // 32768
  unsigned short* aggbuf = (unsigned short*)(w + 30056448);  // 12800000
  unsigned int* binned = (unsigned int*)(w + 42856448);  // 3612672

  const int NB_G = (NN + 63) / 64;     // 782
  const int NB_W = NN * 64 / 256;      // 12500

  hipMemsetAsync(tailc, 0, 784, stream);
  k_bin<<<dim3(NBIN), dim3(256), 0, stream>>>(ei, (const unsigned short*)x, W1, W2,
                                              wp1, wp2, flags, tailc, binned);
  k_degfill<<<dim3(NBKT), dim3(512), 0, stream>>>(binned, tailc, dinv, rowptr, rowend,
                                                  csr_src);

  // ---- layer 1 ----
  k_gemm<0><<<dim3(NB_G), dim3(256), 0, stream>>>(x, wp1, flags, dinv,
                                                  nullptr, nullptr, nullptr, nullptr,
                                                  stats1p, hbuf);
  k_agg<<<dim3(NB_W), dim3(256), 0, stream>>>(hbuf, dinv, rowptr, rowend, csr_src,
                                              b1, flags, aggbuf, stats1p);

  // ---- layer 2 (BN1+PReLU fused into GEMM A-path via stats1p) ----
  k_gemm<2><<<dim3(NB_G), dim3(256), 0, stream>>>(aggbuf, wp2, flags, dinv,
                                                  stats1p, g1, be1, a1, stats2p, hbuf);
  k_agg<<<dim3(NB_W), dim3(256), 0, stream>>>(hbuf, dinv, rowptr, rowend, csr_src,
                                              b2, flags, aggbuf, stats2p);
  k_bn_apply<<<dim3(1024), dim3(256), 0, stream>>>((const unsigned int*)aggbuf, stats2p,
                                                   g2, be2, a2, flags, d_out);
}

// Round 9
// 226.899 us; speedup vs baseline: 1.0352x; 1.0352x over previous
//
#include <hip/hip_runtime.h>
#include <hip/hip_bf16.h>

// 2-layer GCN encoder: (GCNConv -> BatchNorm1d(train) -> PReLU) x 2
// N=50000, E=800000, D=128. Inputs f32 (probed), edge_index int64 (probed),
// output f32. Internal: GEMM/agg buffers bf16, math f32.
//
// R22: revert R21's uint2 agg (regressed +15us: layout change doubled hot
// VGPRs, same lines/edge). Back to R19's 64-lane x 4B whole-row gather with
// scalar-pipe indices -- widened 16 -> 32-deep. Poisson(16) degrees meant
// R19 still took 2 serial LLC round-trips for 57% of nodes (full batch +
// remainder); one 32-edge window = exactly 1 round-trip for 99.99% of nodes.
// Remainder loads indices unconditionally (<=124B overrun inside the 57KB ws
// gap after csr_src), SALU-clamps masked slots to s[0] (dup gathers = L1
// hits), masked branch-free accumulate. Index loads = 2x s_load_dwordx16.
// bin/degfill (R20), gemm (R18), bn unchanged.
//
// ws layout (bytes):
//   [0       .. +200000)   dinv f32[NN]
//   [200704  .. +8)        flags: [0]=int64?, [1]=bf16-floats?
//   [201728  .. +784)      tailc int[196] (zeroed by memset; bucket fills)
//   [404800  .. +200000)   rowptr int[NN] (row starts, gapped CSR)
//   [604816  .. +200000)   rowend int[NN]
//   [806400  .. +65536)    stats1p f32[64][256]
//   [871936  .. +65536)    stats2p f32[64][256]
//   [1048576 .. +3.6MB)    csr_src int[196*4608]
//   [4718592 .. +12.8MB)   hbuf  bf16[NN*DD] packed-slot layout (dinv-scaled)
//   [17518592.. +32768)    wp1 bf16[128*128] swizzled
//   [17551360.. +32768)    wp2 bf16[128*128] swizzled
//   [30056448.. +12.8MB)   aggbuf bf16[NN*DD] row-major
//   [42856448.. +3.6MB)    binned uint[196*4608] packed (src<<16)|dst

typedef __hip_bfloat16 bf16;
typedef __attribute__((ext_vector_type(8))) short short8;   // 8 bf16 = 4 VGPR
typedef __attribute__((ext_vector_type(4))) float f32x4;    // MFMA accumulator

#define NN 50000
#define NE 800000
#define DD 128
#define BN_EPS 1e-5f
#define NBIN 800         // k_bin blocks
#define BIN_CHUNK 1000   // NE / NBIN exactly
#define CAP 4608         // per-bucket capacity (mean 4096 + 8 sigma)
#define NBKT 196         // ceil(50000 / 256)

__device__ __forceinline__ float b2f(bf16 v) { return __bfloat162float(v); }
__device__ __forceinline__ float ldf(const void* p, size_t idx, int isbf) {
  return isbf ? b2f(((const bf16*)p)[idx]) : ((const float*)p)[idx];
}
__device__ __forceinline__ int lde(const void* ei, size_t idx, int is64) {
  return is64 ? (int)((const long long*)ei)[idx] : ((const int*)ei)[idx];
}
__device__ __forceinline__ unsigned int f2bs(float v) {
  bf16 b = __float2bfloat16(v);
  return (unsigned int)*reinterpret_cast<unsigned short*>(&b);
}
__device__ __forceinline__ float bslo(unsigned int u) { return __uint_as_float(u << 16); }
__device__ __forceinline__ float bshi(unsigned int u) { return __uint_as_float(u & 0xFFFF0000u); }
__device__ __forceinline__ float s2f(short v) {
  return __uint_as_float(((unsigned int)(unsigned short)v) << 16);
}

// 800 blocks x 256. Per-block dtype self-probe; block 0 publishes flags;
// blocks 0..63 swizzle W1, 64..127 swizzle W2; all bin their 1000-edge chunk
// into packed binned[] at zero-based bucket counters (tailc pre-zeroed).
// Packed word u = (src<<16) | dst; bucket = (u>>8)&0xFF, local = u&0xFF.
__global__ __launch_bounds__(256) void k_bin(const int* ei_i, const unsigned short* x16,
                                             const void* W1, const void* W2,
                                             unsigned short* wp1, unsigned short* wp2,
                                             int* flags, int* tailc, unsigned int* binned) {
  __shared__ int cnt[NBKT], cur[NBKT], gb[NBKT], sflags[2];
  __shared__ unsigned int ebuf[BIN_CHUNK];  // 4 KB
  const int tid = threadIdx.x;
  const int bid = blockIdx.x;
  if (tid < 64) {
    unsigned long long m1 = __ballot(ei_i[2 * tid + 1] != 0);
    int ex = (x16[2 * tid] >> 7) & 0xFF;
    unsigned long long m2 = __ballot(ex >= 90 && ex <= 140);
    if (tid == 0) {
      sflags[0] = (m1 == 0ull) ? 1 : 0;
      sflags[1] = (__popcll(m2) >= 48) ? 1 : 0;
    }
  }
  if (tid < NBKT) { cnt[tid] = 0; cur[tid] = 0; }
  __syncthreads();
  const int is64 = sflags[0], isbf = sflags[1];
  if (bid == 0 && tid == 0) { flags[0] = is64; flags[1] = isbf; }
  if (bid < 128) {  // W swizzle side-job
    const void* W = bid < 64 ? W1 : W2;
    unsigned short* wp = bid < 64 ? wp1 : wp2;
    int idx = (bid & 63) * 256 + tid;
    int k = idx >> 7, n = idx & 127;
    wp[(k >> 3) * 1024 + n * 8 + (k & 7)] = (unsigned short)f2bs(ldf(W, idx, isbf));
  }
  const void* ei = (const void*)ei_i;
  const int e0 = bid * BIN_CHUNK;
  for (int t = tid; t < BIN_CHUNK; t += 256) {
    int s = lde(ei, (size_t)(e0 + t), is64);
    int d = lde(ei, (size_t)NE + e0 + t, is64);
    ebuf[t] = ((unsigned)s << 16) | (unsigned)d;
    atomicAdd(&cnt[d >> 8], 1);
  }
  __syncthreads();
  if (tid < NBKT && cnt[tid] > 0) gb[tid] = tid * CAP + atomicAdd(&tailc[tid], cnt[tid]);
  __syncthreads();
  for (int t = tid; t < BIN_CHUNK; t += 256) {
    unsigned int u = ebuf[t];
    int b = (int)((u >> 8) & 0xFF);
    int r = atomicAdd(&cur[b], 1);
    binned[gb[b] + r] = u;
  }
}

// Per-bucket (256 nodes): degree hist (LDS) -> dinv/rowptr/rowend, then exact
// CSR fill with LDS cursors. 196 blocks x 512 (edge passes use all 512, scan
// uses 256). Packed u: src=u>>16, local=u&0xFF.
__global__ __launch_bounds__(512) void k_degfill(const unsigned int* binned, const int* tailc,
                                                 float* dinv, int* rowptr, int* rowend,
                                                 int* csr_src) {
  __shared__ int hist[256];
  const int b = blockIdx.x;
  const int t = threadIdx.x;
  if (t < 256) hist[t] = 0;
  __syncthreads();
  const int eb = b * CAP, ee = eb + tailc[b];
  for (int e = eb + t; e < ee; e += 512) atomicAdd(&hist[binned[e] & 0xFF], 1);
  __syncthreads();
  int h = 0;
  if (t < 256) h = hist[t];
  __syncthreads();
  for (int off = 1; off < 256; off <<= 1) {  // inclusive scan over 256
    int u = 0;
    if (t < 256 && t >= off) u = hist[t - off];
    __syncthreads();
    if (t < 256) hist[t] += u;
    __syncthreads();
  }
  if (t < 256) {
    int start = eb + hist[t] - h;  // exclusive prefix, global position
    int node = b * 256 + t;
    if (node < NN) {
      rowptr[node] = start;
      rowend[node] = start + h;
      dinv[node] = rsqrtf((float)(h + 1));  // +1 self-loop
    }
    hist[t] = start;  // repurpose as fill cursor
  }
  __syncthreads();
  for (int e = eb + t; e < ee; e += 512) {
    unsigned int u = binned[e];
    int pos = atomicAdd(&hist[u & 0xFF], 1);
    csr_src[pos] = (int)(u >> 16);
  }
}

// MFMA GEMM, 64 rows/block (782 blocks). out = dinv-prescaled bf16 in
// packed-slot layout: row r, u32 slot s holds bf16 pair (col s, col s+64).
// W pre-swizzled (wp), raw LDS copy. XMODE 0: layer-1 input (probe f32/bf16).
// XMODE 2: aggbuf bf16 + fused BN1 (stats from 64-copy partials statsp).
// Blocks 0..63 zero zstats (consumed by the NEXT kernel's atomics --
// stream-ordered, safe).
template <int XMODE>
__global__ __launch_bounds__(256) void k_gemm(const void* in_, const unsigned short* wp,
                                              const int* flags, const float* dinv,
                                              const float* statsp, const void* g,
                                              const void* be, const void* al,
                                              float* zstats, unsigned int* out) {
  __shared__ alignas(16) short sW[16 * 128 * 8];  // 32 KB
  __shared__ float sSc[DD], sSh[DD], sAl;
  const int isbf = flags[1];
  const int tid = threadIdx.x;

  if (blockIdx.x < 64) zstats[blockIdx.x * 256 + tid] = 0.f;
  {
    const short8* src = (const short8*)wp;
    short8* dst = (short8*)sW;
#pragma unroll
    for (int i = 0; i < 8; i++) dst[tid + i * 256] = src[tid + i * 256];
  }
  if (XMODE == 2) {
    if (tid < DD) {
      float s = 0.f, q = 0.f;
#pragma unroll 8
      for (int k = 0; k < 64; k++) {
        s += statsp[k * 256 + tid];
        q += statsp[k * 256 + 128 + tid];
      }
      const float inv_n = 1.0f / NN;
      float mu = s * inv_n;
      float var = q * inv_n - mu * mu;
      float sc = rsqrtf(var + BN_EPS) * ldf(g, tid, isbf);
      sSc[tid] = sc;
      sSh[tid] = ldf(be, tid, isbf) - mu * sc;
    }
    if (tid == 0) sAl = ldf(al, 0, isbf);
  }
  __syncthreads();

  const int wave = tid >> 6;
  const int lane = tid & 63;
  const int quad = lane >> 4;
  const int m16 = lane & 15;
  const int r0 = blockIdx.x * 64 + wave * 16;

  f32x4 acc[8];
#pragma unroll
  for (int n = 0; n < 8; n++) acc[n] = (f32x4){0.f, 0.f, 0.f, 0.f};

#pragma unroll
  for (int q = 0; q < 4; q++) {
    const int kq = q * 32 + quad * 8;
    short8 af;
    {
      int row = r0 + m16;
      row = row < NN ? row : NN - 1;  // clamp; garbage rows never stored
      if (XMODE == 2) {
        short8 raw = *(const short8*)((const short*)in_ + (size_t)row * DD + kq);
        short8 f;
#pragma unroll
        for (int jj = 0; jj < 8; jj++) {
          float y = s2f(raw[jj]);
          y = y * sSc[kq + jj] + sSh[kq + jj];
          y = y > 0.f ? y : sAl * y;
          f[jj] = (short)f2bs(y);
        }
        af = f;
      } else if (isbf) {
        af = *(const short8*)((const short*)in_ + (size_t)row * DD + kq);
      } else {
        const float* ap = (const float*)in_ + (size_t)row * DD + kq;
        const float4 u0 = *(const float4*)ap;
        const float4 u1 = *(const float4*)(ap + 4);
        float v[8] = {u0.x, u0.y, u0.z, u0.w, u1.x, u1.y, u1.z, u1.w};
        short8 f;
#pragma unroll
        for (int jj = 0; jj < 8; jj++) f[jj] = (short)f2bs(v[jj]);
        af = f;
      }
    }
    const int c = q * 4 + quad;
    const short* bp = sW + c * 1024 + m16 * 8;
#pragma unroll
    for (int n = 0; n < 8; n++) {
      const short8 bfrag = *(const short8*)(bp + n * 128);
      acc[n] = __builtin_amdgcn_mfma_f32_16x16x32_bf16(af, bfrag, acc[n], 0, 0, 0);
    }
  }

#pragma unroll
  for (int r = 0; r < 4; r++) {
    int row = r0 + quad * 4 + r;
    if (row < NN) {
      float di = dinv[row];
      unsigned int* orow = out + (size_t)row * 64;
#pragma unroll
      for (int n = 0; n < 4; n++) {
        unsigned int p = (f2bs(di * acc[n + 4][r]) << 16) | f2bs(di * acc[n][r]);
        orow[n * 16 + m16] = p;
      }
    }
  }
}

// One wave per node (12500 blocks = 50000 waves exactly). R19 structure
// (64-lane x 4B whole-row gather, scalar-pipe uniform indices) widened to a
// 32-deep window: one LLC round-trip covers deg<=32 (99.99% of nodes).
// Remainder: indices loaded unconditionally (2x s_load_dwordx16; <=124B
// overrun stays inside the ws gap after csr_src), masked slots SALU-clamped
// to s[0] (dup gathers = L1 hits), branch-free masked accumulate.
__global__ __launch_bounds__(256) void k_agg(const unsigned int* hs, const float* dinv,
                                             const int* rowptr, const int* rowend,
                                             const int* csr_src, const void* bias,
                                             const int* flags, unsigned short* out,
                                             float* statsp) {
  const int tid = threadIdx.x;
  const int w = (blockIdx.x * 256 + tid) >> 6;   // never >= NN (12500*4 == NN)
  const int lane = tid & 63;
  const float dd_ = dinv[w];
  unsigned int hv = hs[(size_t)w * 64 + lane];
  float ax = bslo(hv), ay = bshi(hv);
  int e = __builtin_amdgcn_readfirstlane(rowptr[w]);
  const int e1 = __builtin_amdgcn_readfirstlane(rowend[w]);

  for (; e + 32 <= e1; e += 32) {
    int s[32];
#pragma unroll
    for (int k = 0; k < 32; k++) s[k] = csr_src[e + k];
    unsigned int v[32];
#pragma unroll
    for (int k = 0; k < 32; k++) v[k] = hs[(size_t)s[k] * 64 + lane];
#pragma unroll
    for (int k = 0; k < 32; k++) { ax += bslo(v[k]); ay += bshi(v[k]); }
  }
  const int r = e1 - e;  // 0..31, wave-uniform
  if (r > 0) {
    int s[32];
#pragma unroll
    for (int k = 0; k < 32; k++) s[k] = csr_src[e + k];  // unconditional
#pragma unroll
    for (int k = 0; k < 32; k++) s[k] = (k < r) ? s[k] : s[0];  // SALU clamp
    unsigned int v[32];
#pragma unroll
    for (int k = 0; k < 32; k++) v[k] = hs[(size_t)s[k] * 64 + lane];
#pragma unroll
    for (int k = 0; k < 32; k++) {
      const float m = (k < r) ? 1.f : 0.f;
      ax += m * bslo(v[k]);
      ay += m * bshi(v[k]);
    }
  }

  int isbf = flags[1];
  float o1 = dd_ * ax + ldf(bias, lane, isbf);
  float o2 = dd_ * ay + ldf(bias, lane + 64, isbf);
  unsigned short* orow = out + (size_t)w * DD;
  orow[lane] = (unsigned short)f2bs(o1);
  orow[lane + 64] = (unsigned short)f2bs(o2);

  __shared__ float rs1[256], rq1[256], rs2[256], rq2[256];
  rs1[tid] = o1; rq1[tid] = o1 * o1;
  rs2[tid] = o2; rq2[tid] = o2 * o2;
  __syncthreads();
  float* p = statsp + (blockIdx.x & 63) * 256;
  if (tid < 64) {  // col tid
    float s = rs1[tid] + rs1[tid + 64] + rs1[tid + 128] + rs1[tid + 192];
    float q = rq1[tid] + rq1[tid + 64] + rq1[tid + 128] + rq1[tid + 192];
    atomicAdd(&p[tid], s);
    atomicAdd(&p[128 + tid], q);
  } else if (tid < 128) {  // col tid (= 64 + lane)
    int l = tid - 64;
    float s = rs2[l] + rs2[l + 64] + rs2[l + 128] + rs2[l + 192];
    float q = rq2[l] + rq2[l + 64] + rq2[l + 128] + rq2[l + 192];
    atomicAdd(&p[tid], s);
    atomicAdd(&p[128 + tid], q);
  }
}

// Final BN+PReLU: 1024 grid-stride blocks. Prologue sums the 64 stat copies
// into LDS sc/sh (one rsqrt per column per block, not per element).
__global__ __launch_bounds__(256) void k_bn_apply(const unsigned int* x32, const float* statsp,
                                                  const void* g, const void* be, const void* al,
                                                  const int* flags, void* out) {
  __shared__ float sSc[DD], sSh[DD], sAl;
  const int tid = threadIdx.x;
  const int isbf = flags[1];
  if (tid < DD) {
    float s = 0.f, q = 0.f;
#pragma unroll 8
    for (int k = 0; k < 64; k++) {
      s += statsp[k * 256 + tid];
      q += statsp[k * 256 + 128 + tid];
    }
    const float inv_n = 1.0f / NN;
    float mu = s * inv_n;
    float var = q * inv_n - mu * mu;
    float sc = rsqrtf(var + BN_EPS) * ldf(g, tid, isbf);
    sSc[tid] = sc;
    sSh[tid] = ldf(be, tid, isbf) - mu * sc;
  }
  if (tid == 0) sAl = ldf(al, 0, isbf);
  __syncthreads();
  const float alpha = sAl;
  for (int i4 = blockIdx.x * 256 + tid; i4 < NN * 32; i4 += gridDim.x * 256) {
    int jq = (i4 & 31) * 4;
    const uint2 xv = ((const uint2*)x32)[i4];
    float xa[4] = {bslo(xv.x), bshi(xv.x), bslo(xv.y), bshi(xv.y)};
    float y[4];
#pragma unroll
    for (int u = 0; u < 4; u++) {
      int j = jq + u;
      float v = xa[u] * sSc[j] + sSh[j];
      y[u] = v > 0.f ? v : alpha * v;
    }
    if (isbf) {
      uint2 o;
      o.x = (f2bs(y[1]) << 16) | f2bs(y[0]);
      o.y = (f2bs(y[3]) << 16) | f2bs(y[2]);
      ((uint2*)out)[i4] = o;
    } else {
      float4 o = {y[0], y[1], y[2], y[3]};
      ((float4*)out)[i4] = o;
    }
  }
}

extern "C" void kernel_launch(void* const* d_in, const int* in_sizes, int n_in,
                              void* d_out, int out_size, void* d_ws, size_t ws_size,
                              hipStream_t stream) {
  const void* x = d_in[0];
  const int* ei = (const int*)d_in[1];
  const void* W1 = d_in[2];
  const void* b1 = d_in[3];
  const void* g1 = d_in[4];
  const void* be1 = d_in[5];
  const void* a1 = d_in[6];
  const void* W2 = d_in[7];
  const void* b2 = d_in[8];
  const void* g2 = d_in[9];
  const void* be2 = d_in[10];
  const void* a2 = d_in[11];

  char* w = (char*)d_ws;
  float* dinv = (float*)w;                              // 200000
  int* flags = (int*)(w + 200704);                      // 8
  int* tailc = (int*)(w + 201728);                      // 784 (196 int)
  int* rowptr = (int*)(w + 404800);                     // 200000
  int* rowend = (int*)(w + 604816);                     // 200000
  float* stats1p = (float*)(w + 806400);                // 65536
  float* stats2p = (float*)(w + 871936);                // 65536
  int* csr_src = (int*)(w + 1048576);                   // 3612672
  unsigned int* hbuf = (unsigned int*)(w + 4718592);    // 12800000
  unsigned short* wp1 = (unsigned short*)(w + 17518592);   // 32768
  unsigned short* wp2 = (unsigned short*)(w + 17551360);   // 32768
  unsigned short* aggbuf = (unsigned short*)(w + 30056448);  // 12800000
  unsigned int* binned = (unsigned int*)(w + 42856448);  // 3612672

  const int NB_G = (NN + 63) / 64;     // 782
  const int NB_W = NN * 64 / 256;      // 12500

  hipMemsetAsync(tailc, 0, 784, stream);
  k_bin<<<dim3(NBIN), dim3(256), 0, stream>>>(ei, (const unsigned short*)x, W1, W2,
                                              wp1, wp2, flags, tailc, binned);
  k_degfill<<<dim3(NBKT), dim3(512), 0, stream>>>(binned, tailc, dinv, rowptr, rowend,
                                                  csr_src);

  // ---- layer 1 ----
  k_gemm<0><<<dim3(NB_G), dim3(256), 0, stream>>>(x, wp1, flags, dinv,
                                                  nullptr, nullptr, nullptr, nullptr,
                                                  stats1p, hbuf);
  k_agg<<<dim3(NB_W), dim3(256), 0, stream>>>(hbuf, dinv, rowptr, rowend, csr_src,
                                              b1, flags, aggbuf, stats1p);

  // ---- layer 2 (BN1+PReLU fused into GEMM A-path via stats1p) ----
  k_gemm<2><<<dim3(NB_G), dim3(256), 0, stream>>>(aggbuf, wp2, flags, dinv,
                                                  stats1p, g1, be1, a1, stats2p, hbuf);
  k_agg<<<dim3(NB_W), dim3(256), 0, stream>>>(hbuf, dinv, rowptr, rowend, csr_src,
                                              b2, flags, aggbuf, stats2p);
  k_bn_apply<<<dim3(1024), dim3(256), 0, stream>>>((const unsigned int*)aggbuf, stats2p,
                                                   g2, be2, a2, flags, d_out);
}

// Round 10
// 219.402 us; speedup vs baseline: 1.0705x; 1.0342x over previous
//
#include <hip/hip_runtime.h>
#include <hip/hip_bf16.h>

// 2-layer GCN encoder: (GCNConv -> BatchNorm1d(train) -> PReLU) x 2
// N=50000, E=800000, D=128. Inputs f32 (probed), edge_index int64 (probed),
// output f32. Internal: GEMM/agg buffers bf16, math f32.
//
// R23 = exact restore of the best-measured configuration (Round-6 source,
// 219.4us): R19 agg (16-deep scalar-pipe gather + predicated 16-remainder),
// R18 gemm (64 rows/block), original bin/degfill (1024-node buckets).
// R20 front-end (neutral), R21 uint2 (-15us), R22 32-deep (-7us) all
// reverted. Agg is closed: 3 independent variants (uint4/uint2/32-deep)
// regressed; the R19 form is the empirical optimum (issue/LLC-bound ~29us).
//
// ws layout (bytes):
//   [0       .. +200000)   dinv f32[NN]
//   [200704  .. +8)        flags: [0]=int64?, [1]=bf16-floats?
//   [404800  .. +200000)   rowptr int[NN] (row starts, gapped CSR)
//   [604816  .. +200000)   rowend int[NN]
//   [805632  .. +256)      tailc int[64] (zeroed by memset; bucket fill counts)
//   [806400  .. +65536)    stats1p f32[64][256]
//   [871936  .. +65536)    stats2p f32[64][256]
//   [1048576 .. +3.7MB)    csr_src int[49*CAP]
//   [4718592 .. +12.8MB)   hbuf  bf16[NN*DD] packed-slot layout (dinv-scaled)
//   [17518592.. +32768)    wp1 bf16[128*128] swizzled
//   [17551360.. +32768)    wp2 bf16[128*128] swizzled
//   [30056448.. +12.8MB)   aggbuf bf16[NN*DD] row-major
//   [42856448.. +3.7MB)    binned uint[49*CAP] packed

typedef __hip_bfloat16 bf16;
typedef __attribute__((ext_vector_type(8))) short short8;   // 8 bf16 = 4 VGPR
typedef __attribute__((ext_vector_type(4))) float f32x4;    // MFMA accumulator

#define NN 50000
#define NE 800000
#define DD 128
#define BN_EPS 1e-5f
#define BIN_CHUNK 3125   // NE / 256 exactly
#define CAP 18432        // per-bucket slot capacity (72*256; mu+16sigma)
#define NBKT 49          // ceil(50000 / 1024)

__device__ __forceinline__ float b2f(bf16 v) { return __bfloat162float(v); }
__device__ __forceinline__ float ldf(const void* p, size_t idx, int isbf) {
  return isbf ? b2f(((const bf16*)p)[idx]) : ((const float*)p)[idx];
}
__device__ __forceinline__ int lde(const void* ei, size_t idx, int is64) {
  return is64 ? (int)((const long long*)ei)[idx] : ((const int*)ei)[idx];
}
__device__ __forceinline__ unsigned int f2bs(float v) {
  bf16 b = __float2bfloat16(v);
  return (unsigned int)*reinterpret_cast<unsigned short*>(&b);
}
__device__ __forceinline__ float bslo(unsigned int u) { return __uint_as_float(u << 16); }
__device__ __forceinline__ float bshi(unsigned int u) { return __uint_as_float(u & 0xFFFF0000u); }
__device__ __forceinline__ float s2f(short v) {
  return __uint_as_float(((unsigned int)(unsigned short)v) << 16);
}

// 256 blocks x 256. Per-block dtype self-probe; block 0 publishes flags;
// blocks 0..63 swizzle W1, 64..127 swizzle W2; all bin their edge chunk into
// packed binned[] at zero-based bucket counters (tailc pre-zeroed).
__global__ __launch_bounds__(256) void k_bin(const int* ei_i, const unsigned short* x16,
                                             const void* W1, const void* W2,
                                             unsigned short* wp1, unsigned short* wp2,
                                             int* flags, int* tailc, unsigned int* binned) {
  __shared__ int cnt[64], cur[64], gb[64], sflags[2];
  __shared__ unsigned int ebuf[BIN_CHUNK];  // 12.5 KB
  const int tid = threadIdx.x;
  const int bid = blockIdx.x;
  if (tid < 64) {
    unsigned long long m1 = __ballot(ei_i[2 * tid + 1] != 0);
    int ex = (x16[2 * tid] >> 7) & 0xFF;
    unsigned long long m2 = __ballot(ex >= 90 && ex <= 140);
    if (tid == 0) {
      sflags[0] = (m1 == 0ull) ? 1 : 0;
      sflags[1] = (__popcll(m2) >= 48) ? 1 : 0;
    }
    cnt[tid] = 0;
    cur[tid] = 0;
  }
  __syncthreads();
  const int is64 = sflags[0], isbf = sflags[1];
  if (bid == 0 && tid == 0) { flags[0] = is64; flags[1] = isbf; }
  if (bid < 128) {  // W swizzle side-job
    const void* W = bid < 64 ? W1 : W2;
    unsigned short* wp = bid < 64 ? wp1 : wp2;
    int idx = (bid & 63) * 256 + tid;
    int k = idx >> 7, n = idx & 127;
    wp[(k >> 3) * 1024 + n * 8 + (k & 7)] = (unsigned short)f2bs(ldf(W, idx, isbf));
  }
  const void* ei = (const void*)ei_i;
  const int e0 = bid * BIN_CHUNK;
  for (int t = tid; t < BIN_CHUNK; t += 256) {
    int s = lde(ei, (size_t)(e0 + t), is64);
    int d = lde(ei, (size_t)NE + e0 + t, is64);
    ebuf[t] = ((unsigned)s << 16) | ((unsigned)(d >> 10) << 10) | (unsigned)(d & 1023);
    atomicAdd(&cnt[d >> 10], 1);
  }
  __syncthreads();
  if (tid < 64 && cnt[tid] > 0) gb[tid] = tid * CAP + atomicAdd(&tailc[tid], cnt[tid]);
  __syncthreads();
  for (int t = tid; t < BIN_CHUNK; t += 256) {
    unsigned int u = ebuf[t];
    int b = (int)((u >> 10) & 63);
    int r = atomicAdd(&cur[b], 1);
    binned[gb[b] + r] = u;
  }
}

// Per-bucket: degree hist (LDS) -> dinv/rowptr/rowend, then exact CSR fill
// with LDS cursors. 49 blocks x 1024. packed u: s=u>>16, dlow=u&1023.
__global__ __launch_bounds__(1024) void k_degfill(const unsigned int* binned, const int* tailc,
                                                  float* dinv, int* rowptr, int* rowend,
                                                  int* csr_src) {
  __shared__ int hist[1024];
  const int b = blockIdx.x;
  const int t = threadIdx.x;
  hist[t] = 0;
  __syncthreads();
  const int eb = b * CAP, ee = eb + tailc[b];
  for (int e = eb + t; e < ee; e += 1024) atomicAdd(&hist[binned[e] & 1023], 1);
  __syncthreads();
  int h = hist[t];
  __syncthreads();
  for (int off = 1; off < 1024; off <<= 1) {  // inclusive scan
    int u = (t >= off) ? hist[t - off] : 0;
    __syncthreads();
    hist[t] += u;
    __syncthreads();
  }
  int start = eb + hist[t] - h;  // exclusive prefix, global position
  int node = b * 1024 + t;
  if (node < NN) {
    rowptr[node] = start;
    rowend[node] = start + h;
    dinv[node] = rsqrtf((float)(h + 1));  // +1 self-loop
  }
  __syncthreads();
  hist[t] = start;  // repurpose as fill cursor
  __syncthreads();
  for (int e = eb + t; e < ee; e += 1024) {
    unsigned int u = binned[e];
    int pos = atomicAdd(&hist[u & 1023], 1);
    csr_src[pos] = (int)(u >> 16);
  }
}

// MFMA GEMM, 64 rows/block (782 blocks). out = dinv-prescaled bf16 in
// packed-slot layout: row r, u32 slot s holds bf16 pair (col s, col s+64).
// W pre-swizzled (wp), raw LDS copy. XMODE 0: layer-1 input (probe f32/bf16).
// XMODE 2: aggbuf bf16 + fused BN1 (stats from 64-copy partials statsp).
// Blocks 0..63 zero zstats (consumed by the NEXT kernel's atomics --
// stream-ordered, safe).
template <int XMODE>
__global__ __launch_bounds__(256) void k_gemm(const void* in_, const unsigned short* wp,
                                              const int* flags, const float* dinv,
                                              const float* statsp, const void* g,
                                              const void* be, const void* al,
                                              float* zstats, unsigned int* out) {
  __shared__ alignas(16) short sW[16 * 128 * 8];  // 32 KB
  __shared__ float sSc[DD], sSh[DD], sAl;
  const int isbf = flags[1];
  const int tid = threadIdx.x;

  if (blockIdx.x < 64) zstats[blockIdx.x * 256 + tid] = 0.f;
  {
    const short8* src = (const short8*)wp;
    short8* dst = (short8*)sW;
#pragma unroll
    for (int i = 0; i < 8; i++) dst[tid + i * 256] = src[tid + i * 256];
  }
  if (XMODE == 2) {
    if (tid < DD) {
      float s = 0.f, q = 0.f;
#pragma unroll 8
      for (int k = 0; k < 64; k++) {
        s += statsp[k * 256 + tid];
        q += statsp[k * 256 + 128 + tid];
      }
      const float inv_n = 1.0f / NN;
      float mu = s * inv_n;
      float var = q * inv_n - mu * mu;
      float sc = rsqrtf(var + BN_EPS) * ldf(g, tid, isbf);
      sSc[tid] = sc;
      sSh[tid] = ldf(be, tid, isbf) - mu * sc;
    }
    if (tid == 0) sAl = ldf(al, 0, isbf);
  }
  __syncthreads();

  const int wave = tid >> 6;
  const int lane = tid & 63;
  const int quad = lane >> 4;
  const int m16 = lane & 15;
  const int r0 = blockIdx.x * 64 + wave * 16;

  f32x4 acc[8];
#pragma unroll
  for (int n = 0; n < 8; n++) acc[n] = (f32x4){0.f, 0.f, 0.f, 0.f};

#pragma unroll
  for (int q = 0; q < 4; q++) {
    const int kq = q * 32 + quad * 8;
    short8 af;
    {
      int row = r0 + m16;
      row = row < NN ? row : NN - 1;  // clamp; garbage rows never stored
      if (XMODE == 2) {
        short8 raw = *(const short8*)((const short*)in_ + (size_t)row * DD + kq);
        short8 f;
#pragma unroll
        for (int jj = 0; jj < 8; jj++) {
          float y = s2f(raw[jj]);
          y = y * sSc[kq + jj] + sSh[kq + jj];
          y = y > 0.f ? y : sAl * y;
          f[jj] = (short)f2bs(y);
        }
        af = f;
      } else if (isbf) {
        af = *(const short8*)((const short*)in_ + (size_t)row * DD + kq);
      } else {
        const float* ap = (const float*)in_ + (size_t)row * DD + kq;
        const float4 u0 = *(const float4*)ap;
        const float4 u1 = *(const float4*)(ap + 4);
        float v[8] = {u0.x, u0.y, u0.z, u0.w, u1.x, u1.y, u1.z, u1.w};
        short8 f;
#pragma unroll
        for (int jj = 0; jj < 8; jj++) f[jj] = (short)f2bs(v[jj]);
        af = f;
      }
    }
    const int c = q * 4 + quad;
    const short* bp = sW + c * 1024 + m16 * 8;
#pragma unroll
    for (int n = 0; n < 8; n++) {
      const short8 bfrag = *(const short8*)(bp + n * 128);
      acc[n] = __builtin_amdgcn_mfma_f32_16x16x32_bf16(af, bfrag, acc[n], 0, 0, 0);
    }
  }

#pragma unroll
  for (int r = 0; r < 4; r++) {
    int row = r0 + quad * 4 + r;
    if (row < NN) {
      float di = dinv[row];
      unsigned int* orow = out + (size_t)row * 64;
#pragma unroll
      for (int n = 0; n < 4; n++) {
        unsigned int p = (f2bs(di * acc[n + 4][r]) << 16) | f2bs(di * acc[n][r]);
        orow[n * 16 + m16] = p;
      }
    }
  }
}

// One wave per node (12500 blocks = 50000 waves exactly). Row range
// [rowptr[w], rowend[w]) in the gapped CSR via readfirstlane -> scalar pipe.
// Main loop: 16-deep gather window. Remainder r in [1,16): ONE predicated
// 16-deep batch (index clamp e+(k<r?k:0); dup addrs = cache hits; masked
// branch-free accumulate) instead of serial 4-deep/1-deep tails.
__global__ __launch_bounds__(256) void k_agg(const unsigned int* hs, const float* dinv,
                                             const int* rowptr, const int* rowend,
                                             const int* csr_src, const void* bias,
                                             const int* flags, unsigned short* out,
                                             float* statsp) {
  const int tid = threadIdx.x;
  const int w = (blockIdx.x * 256 + tid) >> 6;   // never >= NN (12500*4 == NN)
  const int lane = tid & 63;
  const float dd_ = dinv[w];
  unsigned int hv = hs[(size_t)w * 64 + lane];
  float ax = bslo(hv), ay = bshi(hv);
  int e = __builtin_amdgcn_readfirstlane(rowptr[w]);
  const int e1 = __builtin_amdgcn_readfirstlane(rowend[w]);

  for (; e + 16 <= e1; e += 16) {
    int s[16];
#pragma unroll
    for (int k = 0; k < 16; k++) s[k] = csr_src[e + k];
    unsigned int v[16];
#pragma unroll
    for (int k = 0; k < 16; k++) v[k] = hs[(size_t)s[k] * 64 + lane];
#pragma unroll
    for (int k = 0; k < 16; k++) { ax += bslo(v[k]); ay += bshi(v[k]); }
  }
  const int r = e1 - e;  // 0..15, wave-uniform
  if (r > 0) {
    int s[16];
#pragma unroll
    for (int k = 0; k < 16; k++) s[k] = csr_src[e + (k < r ? k : 0)];
    unsigned int v[16];
#pragma unroll
    for (int k = 0; k < 16; k++) v[k] = hs[(size_t)s[k] * 64 + lane];
#pragma unroll
    for (int k = 0; k < 16; k++) {
      const float m = (k < r) ? 1.f : 0.f;
      ax += m * bslo(v[k]);
      ay += m * bshi(v[k]);
    }
  }

  int isbf = flags[1];
  float o1 = dd_ * ax + ldf(bias, lane, isbf);
  float o2 = dd_ * ay + ldf(bias, lane + 64, isbf);
  unsigned short* orow = out + (size_t)w * DD;
  orow[lane] = (unsigned short)f2bs(o1);
  orow[lane + 64] = (unsigned short)f2bs(o2);

  __shared__ float rs1[256], rq1[256], rs2[256], rq2[256];
  rs1[tid] = o1; rq1[tid] = o1 * o1;
  rs2[tid] = o2; rq2[tid] = o2 * o2;
  __syncthreads();
  float* p = statsp + (blockIdx.x & 63) * 256;
  if (tid < 64) {  // col tid
    float s = rs1[tid] + rs1[tid + 64] + rs1[tid + 128] + rs1[tid + 192];
    float q = rq1[tid] + rq1[tid + 64] + rq1[tid + 128] + rq1[tid + 192];
    atomicAdd(&p[tid], s);
    atomicAdd(&p[128 + tid], q);
  } else if (tid < 128) {  // col tid (= 64 + lane)
    int l = tid - 64;
    float s = rs2[l] + rs2[l + 64] + rs2[l + 128] + rs2[l + 192];
    float q = rq2[l] + rq2[l + 64] + rq2[l + 128] + rq2[l + 192];
    atomicAdd(&p[tid], s);
    atomicAdd(&p[128 + tid], q);
  }
}

// Final BN+PReLU: 1024 grid-stride blocks. Prologue sums the 64 stat copies
// into LDS sc/sh (one rsqrt per column per block, not per element).
__global__ __launch_bounds__(256) void k_bn_apply(const unsigned int* x32, const float* statsp,
                                                  const void* g, const void* be, const void* al,
                                                  const int* flags, void* out) {
  __shared__ float sSc[DD], sSh[DD], sAl;
  const int tid = threadIdx.x;
  const int isbf = flags[1];
  if (tid < DD) {
    float s = 0.f, q = 0.f;
#pragma unroll 8
    for (int k = 0; k < 64; k++) {
      s += statsp[k * 256 + tid];
      q += statsp[k * 256 + 128 + tid];
    }
    const float inv_n = 1.0f / NN;
    float mu = s * inv_n;
    float var = q * inv_n - mu * mu;
    float sc = rsqrtf(var + BN_EPS) * ldf(g, tid, isbf);
    sSc[tid] = sc;
    sSh[tid] = ldf(be, tid, isbf) - mu * sc;
  }
  if (tid == 0) sAl = ldf(al, 0, isbf);
  __syncthreads();
  const float alpha = sAl;
  for (int i4 = blockIdx.x * 256 + tid; i4 < NN * 32; i4 += gridDim.x * 256) {
    int jq = (i4 & 31) * 4;
    const uint2 xv = ((const uint2*)x32)[i4];
    float xa[4] = {bslo(xv.x), bshi(xv.x), bslo(xv.y), bshi(xv.y)};
    float y[4];
#pragma unroll
    for (int u = 0; u < 4; u++) {
      int j = jq + u;
      float v = xa[u] * sSc[j] + sSh[j];
      y[u] = v > 0.f ? v : alpha * v;
    }
    if (isbf) {
      uint2 o;
      o.x = (f2bs(y[1]) << 16) | f2bs(y[0]);
      o.y = (f2bs(y[3]) << 16) | f2bs(y[2]);
      ((uint2*)out)[i4] = o;
    } else {
      float4 o = {y[0], y[1], y[2], y[3]};
      ((float4*)out)[i4] = o;
    }
  }
}

extern "C" void kernel_launch(void* const* d_in, const int* in_sizes, int n_in,
                              void* d_out, int out_size, void* d_ws, size_t ws_size,
                              hipStream_t stream) {
  const void* x = d_in[0];
  const int* ei = (const int*)d_in[1];
  const void* W1 = d_in[2];
  const void* b1 = d_in[3];
  const void* g1 = d_in[4];
  const void* be1 = d_in[5];
  const void* a1 = d_in[6];
  const void* W2 = d_in[7];
  const void* b2 = d_in[8];
  const void* g2 = d_in[9];
  const void* be2 = d_in[10];
  const void* a2 = d_in[11];

  char* w = (char*)d_ws;
  float* dinv = (float*)w;                              // 200000
  int* flags = (int*)(w + 200704);                      // 8
  int* rowptr = (int*)(w + 404800);                     // 200000
  int* rowend = (int*)(w + 604816);                     // 200000
  int* tailc = (int*)(w + 805632);                      // 256
  float* stats1p = (float*)(w + 806400);                // 65536
  float* stats2p = (float*)(w + 871936);                // 65536
  int* csr_src = (int*)(w + 1048576);                   // 3612672
  unsigned int* hbuf = (unsigned int*)(w + 4718592);    // 12800000
  unsigned short* wp1 = (unsigned short*)(w + 17518592);   // 32768
  unsigned short* wp2 = (unsigned short*)(w + 17551360);   // 32768
  unsigned short* aggbuf = (unsigned short*)(w + 30056448);  // 12800000
  unsigned int* binned = (unsigned int*)(w + 42856448);  // 3612672

  const int NB_G = (NN + 63) / 64;     // 782
  const int NB_W = NN * 64 / 256;      // 12500

  hipMemsetAsync(tailc, 0, 256, stream);
  k_bin<<<dim3(256), dim3(256), 0, stream>>>(ei, (const unsigned short*)x, W1, W2,
                                             wp1, wp2, flags, tailc, binned);
  k_degfill<<<dim3(NBKT), dim3(1024), 0, stream>>>(binned, tailc, dinv, rowptr, rowend,
                                                   csr_src);

  // ---- layer 1 ----
  k_gemm<0><<<dim3(NB_G), dim3(256), 0, stream>>>(x, wp1, flags, dinv,
                                                  nullptr, nullptr, nullptr, nullptr,
                                                  stats1p, hbuf);
  k_agg<<<dim3(NB_W), dim3(256), 0, stream>>>(hbuf, dinv, rowptr, rowend, csr_src,
                                              b1, flags, aggbuf, stats1p);

  // ---- layer 2 (BN1+PReLU fused into GEMM A-path via stats1p) ----
  k_gemm<2><<<dim3(NB_G), dim3(256), 0, stream>>>(aggbuf, wp2, flags, dinv,
                                                  stats1p, g1, be1, a1, stats2p, hbuf);
  k_agg<<<dim3(NB_W), dim3(256), 0, stream>>>(hbuf, dinv, rowptr, rowend, csr_src,
                                              b2, flags, aggbuf, stats2p);
  k_bn_apply<<<dim3(1024), dim3(256), 0, stream>>>((const unsigned int*)aggbuf, stats2p,
                                                   g2, be2, a2, flags, d_out);
}